// Round 1
// baseline (34.654 us; speedup 1.0000x reference)
//
#include <hip/hip_runtime.h>

// ComplexMixture: B=32, S=128, N=256
// out_r[b,n,m] = sum_s w[b,s]*(r[b,s,n]*r[b,s,m] + i[b,s,n]*i[b,s,m])
// out_i[b,n,m] = sum_s w[b,s]*(i[b,s,n]*r[b,s,m] - r[b,s,n]*i[b,s,m])

constexpr int B = 32;
constexpr int S = 128;
constexpr int N = 256;
constexpr int TILE = 64;   // output tile edge (n and m)
constexpr int KS = 32;     // S-chunk staged in LDS

__global__ __launch_bounds__(256) void ComplexMixture_71313636983193_kernel(
    const float* __restrict__ R, const float* __restrict__ I,
    const float* __restrict__ W, float* __restrict__ Or, float* __restrict__ Oi)
{
    // LDS staging: A-side (n columns, weight-scaled), B-side (m columns)
    __shared__ alignas(16) float Ar[KS][TILE];
    __shared__ alignas(16) float Ai[KS][TILE];
    __shared__ alignas(16) float Br[KS][TILE];
    __shared__ alignas(16) float Bi[KS][TILE];

    const int b  = blockIdx.z;
    const int n0 = blockIdx.y * TILE;
    const int m0 = blockIdx.x * TILE;

    const int t  = threadIdx.x;
    const int tn = t >> 4;   // 0..15 (n direction)
    const int tm = t & 15;   // 0..15 (m direction)

    const float* __restrict__ Rb = R + (size_t)b * S * N;
    const float* __restrict__ Ib = I + (size_t)b * S * N;
    const float* __restrict__ Wb = W + b * S;

    float accR[4][4] = {};
    float accI[4][4] = {};

    for (int s0 = 0; s0 < S; s0 += KS) {
        // Stage KS x TILE for 4 arrays. 32 rows x 16 float4/row = 512 float4
        // per array; 256 threads -> 2 passes. Coalesced along n/m.
        #pragma unroll
        for (int pass = 0; pass < 2; ++pass) {
            const int idx = t + pass * 256;
            const int row = idx >> 4;          // 0..31
            const int c4  = (idx & 15) * 4;    // 0,4,...,60
            const int s   = s0 + row;
            const float w = Wb[s];

            const float4 ra = *(const float4*)&Rb[s * N + n0 + c4];
            const float4 ia = *(const float4*)&Ib[s * N + n0 + c4];
            *(float4*)&Ar[row][c4] = make_float4(w*ra.x, w*ra.y, w*ra.z, w*ra.w);
            *(float4*)&Ai[row][c4] = make_float4(w*ia.x, w*ia.y, w*ia.z, w*ia.w);

            const float4 rb = *(const float4*)&Rb[s * N + m0 + c4];
            const float4 ib = *(const float4*)&Ib[s * N + m0 + c4];
            *(float4*)&Br[row][c4] = rb;
            *(float4*)&Bi[row][c4] = ib;
        }
        __syncthreads();

        #pragma unroll 4
        for (int s = 0; s < KS; ++s) {
            const float4 arv = *(const float4*)&Ar[s][tn * 4];
            const float4 aiv = *(const float4*)&Ai[s][tn * 4];
            const float4 brv = *(const float4*)&Br[s][tm * 4];
            const float4 biv = *(const float4*)&Bi[s][tm * 4];
            const float ar[4] = {arv.x, arv.y, arv.z, arv.w};
            const float ai[4] = {aiv.x, aiv.y, aiv.z, aiv.w};
            const float br[4] = {brv.x, brv.y, brv.z, brv.w};
            const float bi[4] = {biv.x, biv.y, biv.z, biv.w};
            #pragma unroll
            for (int p = 0; p < 4; ++p) {
                #pragma unroll
                for (int q = 0; q < 4; ++q) {
                    accR[p][q] = fmaf(ar[p], br[q], accR[p][q]);
                    accR[p][q] = fmaf(ai[p], bi[q], accR[p][q]);
                    accI[p][q] = fmaf(ai[p], br[q], accI[p][q]);
                    accI[p][q] = fmaf(-ar[p], bi[q], accI[p][q]);
                }
            }
        }
        __syncthreads();
    }

    // Write 4x4 micro-tile, float4 along m (contiguous).
    #pragma unroll
    for (int p = 0; p < 4; ++p) {
        const size_t rowBase = ((size_t)b * N + (n0 + tn * 4 + p)) * N + m0 + tm * 4;
        *(float4*)&Or[rowBase] = make_float4(accR[p][0], accR[p][1], accR[p][2], accR[p][3]);
        *(float4*)&Oi[rowBase] = make_float4(accI[p][0], accI[p][1], accI[p][2], accI[p][3]);
    }
}

extern "C" void kernel_launch(void* const* d_in, const int* in_sizes, int n_in,
                              void* d_out, int out_size, void* d_ws, size_t ws_size,
                              hipStream_t stream) {
    const float* R = (const float*)d_in[0];
    const float* I = (const float*)d_in[1];
    const float* W = (const float*)d_in[2];
    float* Or = (float*)d_out;
    float* Oi = (float*)d_out + (size_t)B * N * N;

    dim3 grid(N / TILE, N / TILE, B);  // 4 x 4 x 32 = 512 blocks
    dim3 block(256);
    ComplexMixture_71313636983193_kernel<<<grid, block, 0, stream>>>(R, I, W, Or, Oi);
}

// Round 2
// 21.838 us; speedup vs baseline: 1.5869x; 1.5869x over previous
//
#include <hip/hip_runtime.h>
#include <hip/hip_fp16.h>

// ComplexMixture: B=32, S=128, N=256
// Or[b,n,m] = sum_s w[b,s]*(r[b,s,n]*r[b,s,m] + i[b,s,n]*i[b,s,m])
// Oi[b,n,m] = sum_s w[b,s]*(i[b,s,n]*r[b,s,m] - r[b,s,n]*i[b,s,m])
//
// Two-kernel plan:
//  T: transpose+convert  R,I [B][S][N] f32  ->  Rt,It [B][N][S] f16 (in d_ws)
//  G: f16 MFMA gemm, A-side weight-scaled at LDS-stage time.

constexpr int B = 32, S = 128, N = 256;

typedef _Float16 f16x8 __attribute__((ext_vector_type(8)));
typedef float    f32x4 __attribute__((ext_vector_type(4)));

union F16x8 { f16x8 v; __half2 h2[4]; };

// ---------------- Kernel T: transpose + fp16 convert ----------------
__global__ __launch_bounds__(256) void ComplexMixture_transpose_kernel(
    const float* __restrict__ R, const float* __restrict__ I,
    _Float16* __restrict__ Rt, _Float16* __restrict__ It)
{
    __shared__ float T1[32][68];   // [s][n] fp32 scratch, 68 = 64 + 4 pad (16B-aligned rows)
    __shared__ float T2[32][68];

    const int b  = blockIdx.z;
    const int s0 = blockIdx.y * 32;
    const int n0 = blockIdx.x * 64;
    const int t  = threadIdx.x;

    const float* Rb = R + ((size_t)b * S + s0) * N + n0;
    const float* Ib = I + ((size_t)b * S + s0) * N + n0;

    // Phase 1: coalesced float4 reads of [32 s][64 n], park in LDS.
    #pragma unroll
    for (int p = 0; p < 2; ++p) {
        const int idx = t + p * 256;
        const int s = idx >> 4, q = idx & 15;
        const float4 r4 = *(const float4*)&Rb[s * N + q * 4];
        const float4 i4 = *(const float4*)&Ib[s * N + q * 4];
        *(float4*)&T1[s][q * 4] = r4;
        *(float4*)&T2[s][q * 4] = i4;
    }
    __syncthreads();

    // Phase 2: read columns (4 consecutive s per n), convert, write [n][s] f16.
    #pragma unroll
    for (int p = 0; p < 2; ++p) {
        const int u  = t + p * 256;
        const int sq = u & 7;        // s-quad 0..7
        const int n  = u >> 3;       // 0..63 across the two passes
        const float a0 = T1[sq*4+0][n], a1 = T1[sq*4+1][n];
        const float a2 = T1[sq*4+2][n], a3 = T1[sq*4+3][n];
        const float c0 = T2[sq*4+0][n], c1 = T2[sq*4+1][n];
        const float c2 = T2[sq*4+2][n], c3 = T2[sq*4+3][n];
        const __half2 ha = __floats2half2_rn(a0, a1), hb = __floats2half2_rn(a2, a3);
        const __half2 hc = __floats2half2_rn(c0, c1), hd = __floats2half2_rn(c2, c3);
        const size_t off = ((size_t)(b * N + n0 + n) * S) + s0 + sq * 4;
        __half2* dr = (__half2*)(Rt + off);
        dr[0] = ha; dr[1] = hb;
        __half2* di = (__half2*)(It + off);
        di[0] = hc; di[1] = hd;
    }
}

// ---------------- Kernel G: MFMA gemm ----------------
// Block: 64x64 (n x m) tile of both outputs for one batch. 4 waves, each 32x32.
// LDS: 4 f16 tiles [64][128] (full K), staged once, one main barrier.
__global__ __launch_bounds__(256) void ComplexMixture_mfma_kernel(
    const _Float16* __restrict__ Rt, const _Float16* __restrict__ It,
    const float* __restrict__ W, float* __restrict__ Or, float* __restrict__ Oi)
{
    __shared__ _Float16 AWR[64][128];   // w * r, A-side (n cols)
    __shared__ _Float16 AWI[64][128];   // w * i
    __shared__ _Float16 BR [64][128];   // r, B-side (m cols)
    __shared__ _Float16 BI [64][128];   // i
    __shared__ __half2  wpk[64];        // packed f16 weight pairs

    const int b  = blockIdx.z;
    const int n0 = blockIdx.y * 64;
    const int m0 = blockIdx.x * 64;
    const int t  = threadIdx.x;

    if (t < 64) {
        wpk[t] = __floats2half2_rn(W[b * S + 2 * t], W[b * S + 2 * t + 1]);
    }
    __syncthreads();

    const _Float16* Anr = Rt + ((size_t)b * N + n0) * S;
    const _Float16* Ani = It + ((size_t)b * N + n0) * S;
    const _Float16* Bmr = Rt + ((size_t)b * N + m0) * S;
    const _Float16* Bmi = It + ((size_t)b * N + m0) * S;

    // Stage: per thread 4 units per array; unit = one f16x8 (8 consecutive s).
    #pragma unroll
    for (int p = 0; p < 4; ++p) {
        const int u   = t + p * 256;
        const int row = u >> 4;      // 0..63
        const int sq  = u & 15;      // s-octet 0..15
        const size_t g = (size_t)row * S + sq * 8;

        F16x8 fr, fi;
        fr.v = *(const f16x8*)&Anr[g];
        fi.v = *(const f16x8*)&Ani[g];
        #pragma unroll
        for (int j = 0; j < 4; ++j) {
            const __half2 w2 = wpk[sq * 4 + j];
            fr.h2[j] = __hmul2(fr.h2[j], w2);
            fi.h2[j] = __hmul2(fi.h2[j], w2);
        }
        *(f16x8*)&AWR[row][sq * 8] = fr.v;
        *(f16x8*)&AWI[row][sq * 8] = fi.v;

        *(f16x8*)&BR[row][sq * 8] = *(const f16x8*)&Bmr[g];
        *(f16x8*)&BI[row][sq * 8] = *(const f16x8*)&Bmi[g];
    }
    __syncthreads();

    // Compute: wave w covers (wn, wm) 32x32 sub-tile.
    const int wv   = t >> 6, lane = t & 63;
    const int wn   = (wv >> 1) * 32, wm = (wv & 1) * 32;
    const int fr16 = lane & 15;   // frag row/col within 16
    const int kb   = lane >> 4;   // k-block 0..3

    f32x4 accR[2][2] = {}, accA[2][2] = {}, accB[2][2] = {};

    #pragma unroll
    for (int ks = 0; ks < 4; ++ks) {          // K = 4 x 32
        const int kofs = ks * 32 + kb * 8;
        f16x8 awr[2], awi[2], br[2], bi[2];
        #pragma unroll
        for (int ns = 0; ns < 2; ++ns) {
            awr[ns] = *(const f16x8*)&AWR[wn + ns * 16 + fr16][kofs];
            awi[ns] = *(const f16x8*)&AWI[wn + ns * 16 + fr16][kofs];
            br[ns]  = *(const f16x8*)&BR [wm + ns * 16 + fr16][kofs];
            bi[ns]  = *(const f16x8*)&BI [wm + ns * 16 + fr16][kofs];
        }
        #pragma unroll
        for (int ns = 0; ns < 2; ++ns) {
            #pragma unroll
            for (int ms = 0; ms < 2; ++ms) {
                accR[ns][ms] = __builtin_amdgcn_mfma_f32_16x16x32_f16(awr[ns], br[ms], accR[ns][ms], 0, 0, 0);
                accR[ns][ms] = __builtin_amdgcn_mfma_f32_16x16x32_f16(awi[ns], bi[ms], accR[ns][ms], 0, 0, 0);
                accA[ns][ms] = __builtin_amdgcn_mfma_f32_16x16x32_f16(awi[ns], br[ms], accA[ns][ms], 0, 0, 0);
                accB[ns][ms] = __builtin_amdgcn_mfma_f32_16x16x32_f16(awr[ns], bi[ms], accB[ns][ms], 0, 0, 0);
            }
        }
    }

    // Epilogue: C/D layout col = lane&15, row = (lane>>4)*4 + reg.
    #pragma unroll
    for (int ns = 0; ns < 2; ++ns) {
        #pragma unroll
        for (int ms = 0; ms < 2; ++ms) {
            #pragma unroll
            for (int r = 0; r < 4; ++r) {
                const int nn = n0 + wn + ns * 16 + kb * 4 + r;
                const int mm = m0 + wm + ms * 16 + fr16;
                const size_t o = ((size_t)b * N + nn) * N + mm;
                Or[o] = accR[ns][ms][r];
                Oi[o] = accA[ns][ms][r] - accB[ns][ms][r];
            }
        }
    }
}

extern "C" void kernel_launch(void* const* d_in, const int* in_sizes, int n_in,
                              void* d_out, int out_size, void* d_ws, size_t ws_size,
                              hipStream_t stream) {
    const float* R = (const float*)d_in[0];
    const float* I = (const float*)d_in[1];
    const float* W = (const float*)d_in[2];
    float* Or = (float*)d_out;
    float* Oi = (float*)d_out + (size_t)B * N * N;

    _Float16* Rt = (_Float16*)d_ws;
    _Float16* It = Rt + (size_t)B * N * S;   // 2 MB each

    ComplexMixture_transpose_kernel<<<dim3(N / 64, S / 32, B), 256, 0, stream>>>(R, I, Rt, It);
    ComplexMixture_mfma_kernel<<<dim3(N / 64, N / 64, B), 256, 0, stream>>>(Rt, It, W, Or, Oi);
}

// Round 3
// 19.198 us; speedup vs baseline: 1.8051x; 1.1375x over previous
//
#include <hip/hip_runtime.h>
#include <hip/hip_fp16.h>

// ComplexMixture: B=32, S=128, N=256
// Or[b,n,m] = sum_s w[b,s]*(r[b,s,n]*r[b,s,m] + i[b,s,n]*i[b,s,m])
// Oi[b,n,m] = sum_s w[b,s]*(i[b,s,n]*r[b,s,m] - r[b,s,n]*i[b,s,m])
//
// Two-kernel plan:
//  T: transpose+convert  R,I [B][S][N] f32  ->  Rt,It [B][N][S] f16 (in d_ws)
//  G: f16 MFMA gemm, A-side weight-scaled at LDS-stage time.
// R3: XOR-swizzled LDS (16B-chunk ^ row bits) on G fragment tiles (was a
//     16-way bank conflict) and on T's transpose scratch; T phase-2 now
//     emits 16B stores.

constexpr int B = 32, S = 128, N = 256;

typedef _Float16 f16x8 __attribute__((ext_vector_type(8)));
typedef float    f32x4 __attribute__((ext_vector_type(4)));

union F16x8 { f16x8 v; __half2 h2[4]; };

// ---------------- Kernel T: transpose + fp16 convert ----------------
__global__ __launch_bounds__(256) void ComplexMixture_transpose_kernel(
    const float* __restrict__ R, const float* __restrict__ I,
    _Float16* __restrict__ Rt, _Float16* __restrict__ It)
{
    // [s][n] fp32 scratch; rows 68 floats (16B-aligned, +pad).
    // 16B chunks within a row are stored at swizzled position q ^ ((s>>3)<<2).
    __shared__ float T1[32][68];
    __shared__ float T2[32][68];

    const int b  = blockIdx.z;
    const int s0 = blockIdx.y * 32;
    const int n0 = blockIdx.x * 64;
    const int t  = threadIdx.x;

    const float* Rb = R + ((size_t)b * S + s0) * N + n0;
    const float* Ib = I + ((size_t)b * S + s0) * N + n0;

    // Phase 1: coalesced float4 reads of [32 s][64 n], park in LDS (swizzled).
    #pragma unroll
    for (int p = 0; p < 2; ++p) {
        const int idx = t + p * 256;
        const int s = idx >> 4, q = idx & 15;
        const int qs = q ^ ((s >> 3) << 2);           // chunk swizzle
        const float4 r4 = *(const float4*)&Rb[s * N + q * 4];
        const float4 i4 = *(const float4*)&Ib[s * N + q * 4];
        *(float4*)&T1[s][qs * 4] = r4;
        *(float4*)&T2[s][qs * 4] = i4;
    }
    __syncthreads();

    // Phase 2: each thread gathers 8 consecutive s for one n, converts,
    // writes one 16B f16x8. p=0 -> real, p=1 -> imag.
    const int n   = t >> 2;       // 0..63
    const int sq8 = t & 3;        // s-octet 0..3
    #pragma unroll
    for (int p = 0; p < 2; ++p) {
        const float (*Tp)[68] = p ? T2 : T1;
        float a[8];
        #pragma unroll
        for (int j = 0; j < 8; ++j) {
            const int s = sq8 * 8 + j;
            const int c = (n >> 2) ^ ((s >> 3) << 2); // chunk swizzle
            a[j] = Tp[s][c * 4 + (n & 3)];
        }
        F16x8 f;
        #pragma unroll
        for (int j = 0; j < 4; ++j)
            f.h2[j] = __floats2half2_rn(a[2 * j], a[2 * j + 1]);
        const size_t off = ((size_t)(b * N + n0 + n) * S) + s0 + sq8 * 8;
        _Float16* dst = (p ? It : Rt) + off;
        *(f16x8*)dst = f.v;
    }
}

// ---------------- Kernel G: MFMA gemm ----------------
// Block: 64x64 (n x m) tile of both outputs for one batch. 4 waves, each 32x32.
// LDS: 4 f16 tiles [64][128] (full K), staged once, one main barrier.
// 16B chunks within each 256B row live at swizzled position chunk ^ (row&7).
__global__ __launch_bounds__(256) void ComplexMixture_mfma_kernel(
    const _Float16* __restrict__ Rt, const _Float16* __restrict__ It,
    const float* __restrict__ W, float* __restrict__ Or, float* __restrict__ Oi)
{
    __shared__ _Float16 AWR[64][128];   // w * r, A-side (n cols)
    __shared__ _Float16 AWI[64][128];   // w * i
    __shared__ _Float16 BR [64][128];   // r, B-side (m cols)
    __shared__ _Float16 BI [64][128];   // i
    __shared__ __half2  wpk[64];        // packed f16 weight pairs

    const int b  = blockIdx.z;
    const int n0 = blockIdx.y * 64;
    const int m0 = blockIdx.x * 64;
    const int t  = threadIdx.x;

    if (t < 64) {
        wpk[t] = __floats2half2_rn(W[b * S + 2 * t], W[b * S + 2 * t + 1]);
    }
    __syncthreads();

    const _Float16* Anr = Rt + ((size_t)b * N + n0) * S;
    const _Float16* Ani = It + ((size_t)b * N + n0) * S;
    const _Float16* Bmr = Rt + ((size_t)b * N + m0) * S;
    const _Float16* Bmi = It + ((size_t)b * N + m0) * S;

    // Stage: per thread 4 units per array; unit = one f16x8 (8 consecutive s).
    // Global read at logical chunk sq; LDS write at swizzled chunk.
    #pragma unroll
    for (int p = 0; p < 4; ++p) {
        const int u   = t + p * 256;
        const int row = u >> 4;                 // 0..63
        const int sq  = u & 15;                 // s-octet 0..15 (logical)
        const int sqs = sq ^ (row & 7);         // swizzled chunk
        const size_t g = (size_t)row * S + sq * 8;

        F16x8 fr, fi;
        fr.v = *(const f16x8*)&Anr[g];
        fi.v = *(const f16x8*)&Ani[g];
        #pragma unroll
        for (int j = 0; j < 4; ++j) {
            const __half2 w2 = wpk[sq * 4 + j];
            fr.h2[j] = __hmul2(fr.h2[j], w2);
            fi.h2[j] = __hmul2(fi.h2[j], w2);
        }
        *(f16x8*)&AWR[row][sqs * 8] = fr.v;
        *(f16x8*)&AWI[row][sqs * 8] = fi.v;

        *(f16x8*)&BR[row][sqs * 8] = *(const f16x8*)&Bmr[g];
        *(f16x8*)&BI[row][sqs * 8] = *(const f16x8*)&Bmi[g];
    }
    __syncthreads();

    // Compute: wave w covers (wn, wm) 32x32 sub-tile.
    const int wv   = t >> 6, lane = t & 63;
    const int wn   = (wv >> 1) * 32, wm = (wv & 1) * 32;
    const int fr16 = lane & 15;   // frag row/col within 16
    const int kb   = lane >> 4;   // k-block 0..3

    f32x4 accR[2][2] = {}, accA[2][2] = {}, accB[2][2] = {};

    #pragma unroll
    for (int ks = 0; ks < 4; ++ks) {          // K = 4 x 32
        f16x8 awr[2], awi[2], br[2], bi[2];
        #pragma unroll
        for (int ns = 0; ns < 2; ++ns) {
            const int ra = wn + ns * 16 + fr16;
            const int rb = wm + ns * 16 + fr16;
            const int ca = ((ks * 4 + kb) ^ (ra & 7)) * 8;  // swizzled chunk
            const int cb = ((ks * 4 + kb) ^ (rb & 7)) * 8;
            awr[ns] = *(const f16x8*)&AWR[ra][ca];
            awi[ns] = *(const f16x8*)&AWI[ra][ca];
            br[ns]  = *(const f16x8*)&BR [rb][cb];
            bi[ns]  = *(const f16x8*)&BI [rb][cb];
        }
        #pragma unroll
        for (int ns = 0; ns < 2; ++ns) {
            #pragma unroll
            for (int ms = 0; ms < 2; ++ms) {
                accR[ns][ms] = __builtin_amdgcn_mfma_f32_16x16x32_f16(awr[ns], br[ms], accR[ns][ms], 0, 0, 0);
                accR[ns][ms] = __builtin_amdgcn_mfma_f32_16x16x32_f16(awi[ns], bi[ms], accR[ns][ms], 0, 0, 0);
                accA[ns][ms] = __builtin_amdgcn_mfma_f32_16x16x32_f16(awi[ns], br[ms], accA[ns][ms], 0, 0, 0);
                accB[ns][ms] = __builtin_amdgcn_mfma_f32_16x16x32_f16(awr[ns], bi[ms], accB[ns][ms], 0, 0, 0);
            }
        }
    }

    // Epilogue: C/D layout col = lane&15, row = (lane>>4)*4 + reg.
    #pragma unroll
    for (int ns = 0; ns < 2; ++ns) {
        #pragma unroll
        for (int ms = 0; ms < 2; ++ms) {
            #pragma unroll
            for (int r = 0; r < 4; ++r) {
                const int nn = n0 + wn + ns * 16 + kb * 4 + r;
                const int mm = m0 + wm + ms * 16 + fr16;
                const size_t o = ((size_t)b * N + nn) * N + mm;
                Or[o] = accR[ns][ms][r];
                Oi[o] = accA[ns][ms][r] - accB[ns][ms][r];
            }
        }
    }
}

extern "C" void kernel_launch(void* const* d_in, const int* in_sizes, int n_in,
                              void* d_out, int out_size, void* d_ws, size_t ws_size,
                              hipStream_t stream) {
    const float* R = (const float*)d_in[0];
    const float* I = (const float*)d_in[1];
    const float* W = (const float*)d_in[2];
    float* Or = (float*)d_out;
    float* Oi = (float*)d_out + (size_t)B * N * N;

    _Float16* Rt = (_Float16*)d_ws;
    _Float16* It = Rt + (size_t)B * N * S;   // 2 MB each

    ComplexMixture_transpose_kernel<<<dim3(N / 64, S / 32, B), 256, 0, stream>>>(R, I, Rt, It);
    ComplexMixture_mfma_kernel<<<dim3(N / 64, N / 64, B), 256, 0, stream>>>(Rt, It, W, Or, Oi);
}